// Round 2
// baseline (182.019 us; speedup 1.0000x reference)
//
#include <hip/hip_runtime.h>
#include <cmath>

static constexpr int NROW = 64;     // K
static constexpr int NCOL = 512;    // L
static constexpr int NBATCH = 1024; // 32*32

// Kernel 1: per-batch Gram matrix G = X X^T, then the 64x64 CGS coefficient
// recurrence  W[i][k] = G[i][k] - sum_{m<k} c[k][m] W[i][m],
// c[k][m] = W[k][m]/W[m][m].  Writes c (scaled) and 1/sqrt(n) into the
// batch's own output slot (used as scratch; overwritten by kernel 2).
__global__ __launch_bounds__(256) void gs_gram_kernel(const float* __restrict__ x,
                                                      float* __restrict__ outbuf)
{
  __shared__ float TT[64][72];   // transposed chunk: TT[col][row], pad->stride 72
  __shared__ float GW[64][65];   // G, overwritten in place by W
  __shared__ float invn[64];

  const int b = blockIdx.x;
  const int t = threadIdx.x;
  const float* __restrict__ X = x + (size_t)b * (NROW * NCOL);

  // map t<136 onto lower-triangular 4x4 tile coords (ta >= tb)
  int ta = 0, tb = 0;
  const bool active = (t < 136);
  if (active) {
    ta = (int)((sqrtf(8.0f * (float)t + 1.0f) - 1.0f) * 0.5f);
    tb = t - (ta * (ta + 1)) / 2;
    while (tb > ta) { ++ta; tb = t - (ta * (ta + 1)) / 2; }
    while (tb < 0)  { --ta; tb = t - (ta * (ta + 1)) / 2; }
  }

  float acc[4][4];
#pragma unroll
  for (int a = 0; a < 4; ++a)
#pragma unroll
    for (int c = 0; c < 4; ++c) acc[a][c] = 0.0f;

  const int r  = t & 63;   // row this thread loads
  const int cq = t >> 6;   // column-group

  for (int ch = 0; ch < 8; ++ch) {
    __syncthreads();  // protect TT reuse
#pragma unroll
    for (int s = 0; s < 4; ++s) {
      const int c0 = 4 * (cq * 4 + s);
      const float4 v = *(const float4*)(X + (size_t)r * NCOL + ch * 64 + c0);
      TT[c0 + 0][r] = v.x;
      TT[c0 + 1][r] = v.y;
      TT[c0 + 2][r] = v.z;
      TT[c0 + 3][r] = v.w;
    }
    __syncthreads();
    if (active) {
#pragma unroll 4
      for (int kk = 0; kk < 64; ++kk) {
        const float4 av = *(const float4*)(&TT[kk][4 * ta]);
        const float4 bv = *(const float4*)(&TT[kk][4 * tb]);
        const float af[4] = {av.x, av.y, av.z, av.w};
        const float bf[4] = {bv.x, bv.y, bv.z, bv.w};
#pragma unroll
        for (int a = 0; a < 4; ++a)
#pragma unroll
          for (int c = 0; c < 4; ++c) acc[a][c] += af[a] * bf[c];
      }
    }
  }

  if (active) {
#pragma unroll
    for (int a = 0; a < 4; ++a)
#pragma unroll
      for (int c = 0; c < 4; ++c) {
        GW[4 * ta + a][4 * tb + c] = acc[a][c];   // lower
        GW[4 * tb + c][4 * ta + a] = acc[a][c];   // mirror
      }
  }
  __syncthreads();

  // W-recurrence (in place on GW), single wave, lane = matrix row i.
  // Valid for the full square; only lower part + diag is consumed later.
  if (t < 64) {
    const int i = t;
    for (int k = 0; k < 64; ++k) {
      float w = GW[i][k];
      for (int m = 0; m < k; ++m) {
        const float ckm = GW[k][m] * invn[m];   // uniform broadcast reads
        w -= ckm * GW[i][m];                    // conflict-free vector read
      }
      GW[i][k] = w;
      if (i == k) invn[k] = 1.0f / w;           // n_k = W[k][k]
    }
  }
  __syncthreads();

  // emit c[i][m] = W[i][m]/n_m (full 64x64; only m<i used) + invsqrt norms
  float* __restrict__ slot = outbuf + (size_t)b * (NROW * NCOL);
#pragma unroll
  for (int q = 0; q < 16; ++q) {
    const int idx = t + 256 * q;
    const int ii = idx >> 6;
    const int mm = idx & 63;
    slot[idx] = GW[ii][mm] * invn[mm];
  }
  if (t < 64) {
    slot[4096 + t] = 1.0f / sqrtf(GW[t][t]);
  }
}

// Kernel 2: forward substitution q_i = x_i - sum_{m<i} c[i][m] q_m, then
// row normalization.  Thread t owns columns 2t, 2t+1 of all 64 rows in
// registers; coefficients are LDS broadcast reads.
__global__ __launch_bounds__(256) void gs_apply_kernel(const float* __restrict__ x,
                                                       float* __restrict__ outbuf)
{
  __shared__ float cL[64 * 64];
  __shared__ float sL[64];

  const int b = blockIdx.x;
  const int t = threadIdx.x;
  float* __restrict__ slot = outbuf + (size_t)b * (NROW * NCOL);

  // pull this batch's coefficients into LDS BEFORE any output store
#pragma unroll
  for (int q = 0; q < 16; ++q) cL[t + 256 * q] = slot[t + 256 * q];
  if (t < 64) sL[t] = slot[4096 + t];
  __syncthreads();

  const float* __restrict__ X = x + (size_t)b * (NROW * NCOL);
  float ax[64], ay[64];
#pragma unroll
  for (int rr = 0; rr < 64; ++rr) {
    const float2 v = *(const float2*)(X + (size_t)rr * NCOL + 2 * t);
    ax[rr] = v.x; ay[rr] = v.y;
  }

  // fully-unrolled triangular solve: constant register indices throughout
#pragma unroll
  for (int i = 1; i < 64; ++i) {
#pragma unroll
    for (int m = 0; m < i; ++m) {
      const float c = cL[i * 64 + m];
      ax[i] -= c * ax[m];
      ay[i] -= c * ay[m];
    }
  }

#pragma unroll
  for (int rr = 0; rr < 64; ++rr) {
    const float s = sL[rr];
    float2 v;
    v.x = ax[rr] * s;
    v.y = ay[rr] * s;
    *(float2*)(slot + (size_t)rr * NCOL + 2 * t) = v;
  }
}

extern "C" void kernel_launch(void* const* d_in, const int* in_sizes, int n_in,
                              void* d_out, int out_size, void* d_ws, size_t ws_size,
                              hipStream_t stream) {
  const float* x = (const float*)d_in[0];
  float* out = (float*)d_out;
  gs_gram_kernel<<<NBATCH, 256, 0, stream>>>(x, out);
  gs_apply_kernel<<<NBATCH, 256, 0, stream>>>(x, out);
}